// Round 10
// baseline (1134.502 us; speedup 1.0000x reference)
//
#include <hip/hip_runtime.h>
#include <math.h>

#define ANUM 3
#define CNUM 3
#define BNUM 32
#define MNUM 16
#define CH 24      // ANUM*(5+CNUM)
#define NSEG 96
#define CAP 16384  // per-segment candidate capacity (6.3 MB total)
#define BCAP 768   // per-block max pushes = 256 threads * 3 anchors (no overflow)

// All cross-block state in static device memory (zero-initialized at load).
// Each iteration self-cleans -> no init kernel needed.
__device__ __align__(16) float g_cand[(size_t)NSEG*CAP];
__device__ int   g_ccnt[NSEG];
__device__ float g_acc[NSEG*5];
__device__ float g_lsum[3];
__device__ int   g_arr[NSEG];
__device__ int   g_done;

__device__ __forceinline__ float wred(float v){
  #pragma unroll
  for (int off=32; off; off>>=1) v += __shfl_down(v, off, 64);
  return v;
}

// Relaxed agent-scope arrival (verified r8/r9: acq_rel costs L2 wb/inv storms;
// relaxed + the vmcnt(0) the compiler emits before s_barrier is sufficient
// because ALL cross-block data moves through coherence-point atomics).
__device__ __forceinline__ int arrive(int* ctr){
  asm volatile("s_waitcnt vmcnt(0)" ::: "memory");
  return __hip_atomic_fetch_add(ctr, 1, __ATOMIC_RELAXED, __HIP_MEMORY_SCOPE_AGENT);
}
__device__ __forceinline__ int aload_i(const int* p){
  return __hip_atomic_load(p, __ATOMIC_RELAXED, __HIP_MEMORY_SCOPE_AGENT);
}
__device__ __forceinline__ float aload_f(const float* p){
  return __hip_atomic_load(p, __ATOMIC_RELAXED, __HIP_MEMORY_SCOPE_AGENT);
}
__device__ __forceinline__ void astore_f(float* p, float v){
  __hip_atomic_store(p, v, __ATOMIC_RELAXED, __HIP_MEMORY_SCOPE_AGENT);
}

// Exact per-anchor recompute for the fallback path (no prune; zero-inter
// updates change best only between -1 and 0, both classified identically).
template<int H, int W>
__device__ float recompute_negval(const float* __restrict__ pred,
    const float* sbox, int b, int n)
{
  constexpr int HW = H*W;
  const int a = n % 3;
  const int pixn = n / 3;
  const int h = pixn / W, w = pixn % W;
  const float cx = ((float)w+0.5f)/(float)W;
  const float cy = ((float)h+0.5f)/(float)H;
  const float sz = (a==0)?0.08f:((a==1)?0.16f:0.28f);
  const float hs = sz*0.5f;
  const float ax0=cx-hs, ay0=cy-hs, ax1=cx+hs, ay1=cy+hs;
  const float areaA=(ax1-ax0)*(ay1-ay0);
  float bi=-1.f, bu=1.f;
  for (int m=0;m<MNUM;m++){
    const float bcx=sbox[4*m], bcy=sbox[4*m+1], bw=sbox[4*m+2], bh=sbox[4*m+3];
    const float bx0=bcx-bw*0.5f, by0=bcy-bh*0.5f, bx1=bcx+bw*0.5f, by1=bcy+bh*0.5f;
    float iw=fminf(ax1,bx1)-fmaxf(ax0,bx0);
    float ih=fminf(ay1,by1)-fmaxf(ay0,by0);
    iw=fmaxf(iw,0.f); ih=fmaxf(ih,0.f);
    const float inter=iw*ih;
    const float areaB=(bx1-bx0)*(by1-by0);
    const float uni=areaA+areaB-inter+1e-9f;
    if (inter*bu > bi*uni){ bi=inter; bu=uni; }
  }
  const float best=bi/bu;
  const bool pos = best>=0.5f;
  const bool neg = best<0.4f;
  const float o = pred[(size_t)b*CH*HW + (a*8+4)*HW + pixn];
  const float sp = log1pf(expf(-fabsf(o)));
  const float obj_all = fmaxf(o,0.f) - (pos?o:0.f) + sp;
  return neg ? obj_all : -1.f;
}

// Per-pixel anchor work: prune, classify, losses, candidate push.
template<int H, int W, int SCALE>
__device__ __forceinline__ void k1_work(
    const float* __restrict__ pred, const float* sbox, const int* slab,
    int b, int pix, float* slv, int* s_loc, float* f)
{
  constexpr int HW = H*W;
  const bool valid = (pix < HW);
  const int pp = valid ? pix : 0;
  const int h = pp / W, w = pp % W;
  const float cx = ((float)w + 0.5f)/(float)W;
  const float cy = ((float)h + 0.5f)/(float)H;
  const float THR = (SCALE==0) ? 1.5f : ((SCALE==1) ? 1.0f : 0.0f);

  const float* pb = pred + (size_t)b*CH*HW;
  float obj[3];
  #pragma unroll
  for (int a=0;a<3;a++) obj[a] = pb[(a*8+4)*HW + pp];   // coalesced

  float ax0[3],ay0[3],ax1[3],ay1[3],areaA[3];
  #pragma unroll
  for (int a=0;a<3;a++){
    const float sz=(a==0)?0.08f:((a==1)?0.16f:0.28f);
    const float hs=sz*0.5f;
    ax0[a]=cx-hs; ay0[a]=cy-hs; ax1[a]=cx+hs; ay1[a]=cy+hs;
    areaA[a]=(ax1[a]-ax0[a])*(ay1[a]-ay0[a]);
  }
  const float axr = cx + 0.14f, axl = cx - 0.14f;   // largest-anchor prune box
  const float ayr = cy + 0.14f, ayl = cy - 0.14f;

  float bi[3]={-1.f,-1.f,-1.f}, bu[3]={1.f,1.f,1.f};
  int bm[3]={0,0,0};
  #pragma unroll 4
  for (int m=0;m<MNUM;m++){
    const float bcx=sbox[4*m], bcy=sbox[4*m+1], bw=sbox[4*m+2], bh=sbox[4*m+3];
    const float bx0=bcx-bw*0.5f, by0=bcy-bh*0.5f, bx1=bcx+bw*0.5f, by1=bcy+bh*0.5f;
    const float iwb = fminf(axr,bx1) - fmaxf(axl,bx0);
    const float ihb = fminf(ayr,by1) - fmaxf(ayl,by0);
    if (iwb <= 0.f || ihb <= 0.f) continue;   // exact skip (monotone in hs)
    const float areaB=(bx1-bx0)*(by1-by0);
    #pragma unroll
    for (int a=0;a<3;a++){
      float iw=fminf(ax1[a],bx1)-fmaxf(ax0[a],bx0);
      float ih=fminf(ay1[a],by1)-fmaxf(ay0[a],by0);
      iw=fmaxf(iw,0.f); ih=fmaxf(ih,0.f);
      const float inter=iw*ih;
      const float uni=areaA[a]+areaB-inter+1e-9f;
      if (inter*bu[a] > bi[a]*uni){ bi[a]=inter; bu[a]=uni; bm[a]=m; }
    }
  }

  const int lane = threadIdx.x & 63;
  #pragma unroll
  for (int a=0;a<3;a++){
    const float best = bi[a]/bu[a];       // same operands as reference iou
    const bool pos = best >= 0.5f;
    const bool neg = best < 0.4f;
    const float o = obj[a];
    const float sp = log1pf(expf(-fabsf(o)));
    const float obj_all = fmaxf(o,0.f) - (pos? o:0.f) + sp;

    // wave-aggregated candidate push (<=768 per block; BCAP never overflows)
    const bool push = valid && neg && (obj_all >= THR);
    unsigned long long pm = __ballot(push ? 1 : 0);
    if (push){
      const int leader = (int)__ffsll((unsigned long long)pm) - 1;
      int wb2 = 0;
      if (lane == leader) wb2 = atomicAdd(s_loc, (int)__popcll(pm));
      wb2 = __shfl(wb2, leader, 64);
      slv[wb2 + (int)__popcll(pm & ((1ull<<lane)-1ull))] = obj_all;
    }

    if (valid){
      if (neg) f[1] += 1.f;
      if (pos){
        f[0]+=1.f; f[2]+=obj_all;
        const int midx=bm[a];
        int ct = slab[midx]-1; ct = ct<0?0:(ct>CNUM-1?CNUM-1:ct);
        const int cb=a*8;
        float c0=pb[(cb+5)*HW+pp], c1=pb[(cb+6)*HW+pp], c2=pb[(cb+7)*HW+pp];
        float mx=fmaxf(c0,fmaxf(c1,c2));
        float lse=mx+logf(expf(c0-mx)+expf(c1-mx)+expf(c2-mx));
        float csel=(ct==0)?c0:((ct==1)?c1:c2);
        f[3]+=lse-csel;
        const float sz=(a==0)?0.08f:((a==1)?0.16f:0.28f);
        float mcx=sbox[4*midx],mcy=sbox[4*midx+1],mw=sbox[4*midx+2],mh=sbox[4*midx+3];
        float t0=(mcx-cx)/sz,t1=(mcy-cy)/sz,t2=logf(mw/sz),t3=logf(mh/sz);
        float l0=pb[(cb+0)*HW+pp],l1=pb[(cb+1)*HW+pp],l2=pb[(cb+2)*HW+pp],l3=pb[(cb+3)*HW+pp];
        float ssum=0.f,d;
        d=fabsf(l0-t0); ssum+=(d<1.f)?(0.5f*d*d):(d-0.5f);
        d=fabsf(l1-t1); ssum+=(d<1.f)?(0.5f*d*d):(d-0.5f);
        d=fabsf(l2-t2); ssum+=(d<1.f)?(0.5f*d*d):(d-0.5f);
        d=fabsf(l3-t3); ssum+=(d<1.f)?(0.5f*d*d):(d-0.5f);
        f[4]+=ssum;
      }
    }
  }
}

// Full per-segment pipeline: anchor work -> flush -> arrival -> (last block)
// exact top-k over candidates -> loss -> (very last) output. Self-cleans.
template<int H, int W, int SCALE>
__device__ __forceinline__ void seg_run(
    const float* __restrict__ pred, const float* sbox, const int* slab,
    float* slv, int* p_sloc, float (*red)[4], int* hist, int* misc,
    float* fnp, int b, int cix, int nblk, float* scratch, float* out)
{
  constexpr int HW = H*W;
  constexpr int N = HW*ANUM;
  const int g = SCALE*BNUM + b;

  float f[5] = {0.f,0.f,0.f,0.f,0.f};
  k1_work<H,W,SCALE>(pred, sbox, slab, b, cix*256 + (int)threadIdx.x, slv, p_sloc, f);

  const int lane = threadIdx.x & 63, wv = threadIdx.x >> 6;
  __syncthreads();                      // all pushes done; s_loc final
  #pragma unroll
  for (int q=0;q<5;q++){
    float r = wred(f[q]);
    if (lane==0) red[q][wv] = r;
  }
  __syncthreads();
  if (threadIdx.x < 5){
    const int q = threadIdx.x;
    float t = red[q][0]+red[q][1]+red[q][2]+red[q][3];
    if (t != 0.f) atomicAdd(&g_acc[g*5+q], t);
  }
  const int n = *p_sloc;
  if (threadIdx.x == 0) misc[3] = (n > 0) ? atomicAdd(&g_ccnt[g], n) : 0;
  __syncthreads();
  const int gbase = misc[3];
  for (int i=threadIdx.x; i<n; i+=256){
    const int idx = gbase + i;
    if (idx < CAP) astore_f(&g_cand[(size_t)g*CAP + idx], slv[i]);
  }
  __syncthreads();                      // compiler drains vmcnt at barrier

  if (threadIdx.x==0) misc[2] = (arrive(&g_arr[g]) == nblk-1) ? 1 : 0;
  __syncthreads();
  if (!misc[2]) return;

  // ---------- fin (last block of this segment) ----------
  const int C_total = aload_i(&g_ccnt[g]);
  if (threadIdx.x==0){
    fnp[0] = aload_f(&g_acc[g*5+0]);
    fnp[1] = aload_f(&g_acc[g*5+1]);
  }
  __syncthreads();
  const float npos_f = fnp[0];
  const int npos = (int)(npos_f + 0.5f);
  const int avail = (int)(fnp[1] + 0.5f);
  const int k = (npos==0) ? (avail < 100 ? avail : 100)
                          : (3*npos < avail ? 3*npos : avail);

  float ss = 0.f, ns = 0.f;
  if (k > 0){
    const bool cpath = (C_total <= CAP) && (k <= C_total);
    const float* src; int M;
    if (cpath){
      src = g_cand + (size_t)g*CAP; M = C_total;
    } else {
      // fallback (never on benign data): exact recompute into own scratch
      for (int i=threadIdx.x; i<N; i+=256)
        scratch[i] = recompute_negval<H,W>(pred, sbox, b, i);
      __syncthreads();
      src = scratch; M = N;
    }
    // exact k-th largest via 4x8-bit MSB-first radix (values > 0: uint order)
    unsigned prefix = 0, pmask = 0; int rem = k;
    #pragma unroll
    for (int p=0;p<4;p++){
      const int shift = 24 - 8*p;
      hist[threadIdx.x] = 0;
      __syncthreads();
      for (int i=threadIdx.x; i<M; i+=256){
        float v = aload_f(src + i);
        if (v < 0.f) continue;
        unsigned u = __float_as_uint(v);
        if ((u & pmask) == prefix) atomicAdd(&hist[(u>>shift)&255], 1);
      }
      __syncthreads();
      if (threadIdx.x==0){
        int cum=0;
        for (int j=255;j>=0;j--){
          cum += hist[j];
          if (cum >= rem){ misc[0]=j; misc[1] = rem-(cum-hist[j]); break; }
        }
      }
      __syncthreads();
      prefix |= ((unsigned)misc[0]) << shift;
      pmask  |= (255u << shift);
      rem = misc[1];
      __syncthreads();
    }
    const float thr = __uint_as_float(prefix);
    for (int i=threadIdx.x; i<M; i+=256){
      float v = aload_f(src + i);
      if (v >= thr){ ss += v; ns += 1.f; }   // thr > 0 excludes -1 sentinels
    }
  }

  float r0 = wred(ss), r1 = wred(ns);
  if (lane==0){ red[0][wv]=r0; red[1][wv]=r1; }
  __syncthreads();
  if (threadIdx.x==0){
    float sstot = red[0][0]+red[0][1]+red[0][2]+red[0][3];
    float nstot = red[1][0]+red[1][1]+red[1][2]+red[1][3];
    float cnt2 = npos_f + nstot;
    float ag2 = aload_f(&g_acc[g*5+2]);
    float ag3 = aload_f(&g_acc[g*5+3]);
    float ag4 = aload_f(&g_acc[g*5+4]);
    float lo = (cnt2 > 0.f) ? (ag2 + sstot)/cnt2 : 0.f;
    float lc = (npos > 0) ? ag3/npos_f : 0.f;
    float ll = (npos > 0) ? ag4/(npos_f*4.f) : 0.f;
    atomicAdd(&g_lsum[0], lo);
    atomicAdd(&g_lsum[1], lc);
    atomicAdd(&g_lsum[2], ll);
    if (arrive(&g_done) == NSEG-1){
      float L0 = aload_f(&g_lsum[0]);
      float L1 = aload_f(&g_lsum[1]);
      float L2 = aload_f(&g_lsum[2]);
      float lo2 = L0*(1.f/32.f), lc2 = L1*(1.f/32.f), ll2 = L2*(1.f/32.f);
      out[0]=lo2; out[1]=lc2; out[2]=ll2; out[3]=lo2+lc2+ll2;
      g_lsum[0]=0.f; g_lsum[1]=0.f; g_lsum[2]=0.f; g_done=0;
    }
  }

  // self-clean this segment's state for the next iteration
  __syncthreads();
  if (threadIdx.x < 5) g_acc[g*5 + threadIdx.x] = 0.f;
  if (threadIdx.x == 5) g_ccnt[g] = 0;
  if (threadIdx.x == 6) g_arr[g] = 0;
}

__global__ __launch_bounds__(256) void k_all(
    const float* __restrict__ pred0, const float* __restrict__ pred1,
    const float* __restrict__ pred2, const float* __restrict__ boxes,
    const int* __restrict__ labels, float* __restrict__ ws,
    float* __restrict__ out)
{
  __shared__ float sbox[MNUM*4];
  __shared__ int   slab[MNUM];
  __shared__ float slv[BCAP];          // 3 KB candidate buffer
  __shared__ int   s_loc;
  __shared__ float red[5][4];
  __shared__ int   hist[256];          // fin radix
  __shared__ int   misc[4];            // s_bin, s_rem, s_lastb, s_gbase
  __shared__ float fnp[2];

  const int b = blockIdx.y;
  if (threadIdx.x < MNUM*4) sbox[threadIdx.x] = boxes[b*MNUM*4 + threadIdx.x];
  else if (threadIdx.x < MNUM*5) slab[threadIdx.x - MNUM*4] = labels[b*MNUM + (threadIdx.x - MNUM*4)];
  if (threadIdx.x == 0) s_loc = 0;
  __syncthreads();

  const int c = blockIdx.x;   // 0..131 : 100 s0 + 25 s1 + 7 s2
  if (c < 100)
    seg_run<160,160,0>(pred0, sbox, slab, slv, &s_loc, red, hist, misc, fnp,
                       b, c, 100, ws + (size_t)b*76800, out);
  else if (c < 125)
    seg_run<80,80,1>(pred1, sbox, slab, slv, &s_loc, red, hist, misc, fnp,
                     b, c-100, 25, ws + (size_t)BNUM*76800 + (size_t)b*19200, out);
  else
    seg_run<40,40,2>(pred2, sbox, slab, slv, &s_loc, red, hist, misc, fnp,
                     b, c-125, 7, ws + (size_t)BNUM*(76800+19200) + (size_t)b*4800, out);
}

extern "C" void kernel_launch(void* const* d_in, const int* in_sizes, int n_in,
                              void* d_out, int out_size, void* d_ws, size_t ws_size,
                              hipStream_t stream)
{
  const float* pred0 = (const float*)d_in[0];
  const float* pred1 = (const float*)d_in[1];
  const float* pred2 = (const float*)d_in[2];
  const float* boxes = (const float*)d_in[6];
  const int*   labels = (const int*)d_in[7];
  float* out = (float*)d_out;
  float* ws  = (float*)d_ws;    // scratch used ONLY by the exact fallback

  k_all<<<dim3(132,32), 256, 0, stream>>>(pred0, pred1, pred2, boxes, labels, ws, out);
}

// Round 11
// 394.685 us; speedup vs baseline: 2.8744x; 2.8744x over previous
//
#include <hip/hip_runtime.h>
#include <math.h>

#define ANUM 3
#define CNUM 3
#define BNUM 32
#define MNUM 16
#define CH 24      // ANUM*(5+CNUM)
#define NSEG 96
#define CAP 32768  // per-segment candidate capacity (12.6 MB static)
#define BCAP 768   // per-block max pushes = 256 threads * 3 anchors (no overflow)

// All cross-block state in static device memory (zero-initialized at load).
// Each iteration self-cleans -> no init kernel needed.
__device__ __align__(16) float g_cand[(size_t)NSEG*CAP];
__device__ int   g_ccnt[NSEG];
__device__ float g_acc[NSEG*5];
__device__ float g_lsum[3];
__device__ int   g_arr[NSEG];
__device__ int   g_done;

__device__ __forceinline__ float wred(float v){
  #pragma unroll
  for (int off=32; off; off>>=1) v += __shfl_down(v, off, 64);
  return v;
}

// Relaxed agent-scope arrival (r8/r9: acq_rel causes L2 wb/inv storms;
// relaxed + vmcnt(0) suffices: all cross-block data moves through
// coherence-point atomics).
__device__ __forceinline__ int arrive(int* ctr){
  asm volatile("s_waitcnt vmcnt(0)" ::: "memory");
  return __hip_atomic_fetch_add(ctr, 1, __ATOMIC_RELAXED, __HIP_MEMORY_SCOPE_AGENT);
}
__device__ __forceinline__ int aload_i(const int* p){
  return __hip_atomic_load(p, __ATOMIC_RELAXED, __HIP_MEMORY_SCOPE_AGENT);
}
__device__ __forceinline__ float aload_f(const float* p){
  return __hip_atomic_load(p, __ATOMIC_RELAXED, __HIP_MEMORY_SCOPE_AGENT);
}
__device__ __forceinline__ void astore_f(float* p, float v){
  __hip_atomic_store(p, v, __ATOMIC_RELAXED, __HIP_MEMORY_SCOPE_AGENT);
}

// Wave-aggregated histogram add (proven r1/r2): lanes with equal bin elect a
// leader doing ONE atomicAdd of popcount(peers). Safe under partial exec
// (__ballot masks to active lanes). Essential here: fin candidates are
// tail-concentrated -> without this, 64-way same-address LDS serialization
// (the r10 1.2ms pathology).
__device__ __forceinline__ void agg_hist_add(int* hist, unsigned bin, bool valid){
  unsigned long long peers = __ballot(valid ? 1 : 0);
  #pragma unroll
  for (int i = 0; i < 8; i++){
    unsigned long long bb = __ballot((valid && (bin & (1u<<i))) ? 1 : 0);
    peers &= ((bin >> i) & 1u) ? bb : ~bb;
  }
  if (valid){
    const int lane = threadIdx.x & 63;
    if ((peers & ((1ull << lane) - 1ull)) == 0ull)
      atomicAdd(&hist[bin], (int)__popcll(peers));
  }
}

// Exact per-anchor recompute for the (provably-dead on benign data)
// fallback path.
template<int H, int W>
__device__ float recompute_negval(const float* __restrict__ pred,
    const float* sbox, int b, int n)
{
  constexpr int HW = H*W;
  const int a = n % 3;
  const int pixn = n / 3;
  const int h = pixn / W, w = pixn % W;
  const float cx = ((float)w+0.5f)/(float)W;
  const float cy = ((float)h+0.5f)/(float)H;
  const float sz = (a==0)?0.08f:((a==1)?0.16f:0.28f);
  const float hs = sz*0.5f;
  const float ax0=cx-hs, ay0=cy-hs, ax1=cx+hs, ay1=cy+hs;
  const float areaA=(ax1-ax0)*(ay1-ay0);
  float bi=-1.f, bu=1.f;
  for (int m=0;m<MNUM;m++){
    const float bcx=sbox[4*m], bcy=sbox[4*m+1], bw=sbox[4*m+2], bh=sbox[4*m+3];
    const float bx0=bcx-bw*0.5f, by0=bcy-bh*0.5f, bx1=bcx+bw*0.5f, by1=bcy+bh*0.5f;
    float iw=fminf(ax1,bx1)-fmaxf(ax0,bx0);
    float ih=fminf(ay1,by1)-fmaxf(ay0,by0);
    iw=fmaxf(iw,0.f); ih=fmaxf(ih,0.f);
    const float inter=iw*ih;
    const float areaB=(bx1-bx0)*(by1-by0);
    const float uni=areaA+areaB-inter+1e-9f;
    if (inter*bu > bi*uni){ bi=inter; bu=uni; }
  }
  const float best=bi/bu;
  const bool pos = best>=0.5f;
  const bool neg = best<0.4f;
  const float o = pred[(size_t)b*CH*HW + (a*8+4)*HW + pixn];
  const float sp = log1pf(expf(-fabsf(o)));
  const float obj_all = fmaxf(o,0.f) - (pos?o:0.f) + sp;
  return neg ? obj_all : -1.f;
}

// Per-pixel anchor work: prune, classify, losses, candidate push.
// THR per scale chosen so candidates PROVABLY cover top-k:
//  k = 3*npos <= 3*16*73 = 3504  (IoU>=0.5 forces center offset <= anchor/3
//  => <=73 anchors/box);  C(s0)~=0.29*74K=21.9K, C(s1)~=0.76*18.8K=14.3K,
//  C(s2)=all negs >= avail >= k (structural).  k << C, C < CAP.
template<int H, int W, int SCALE>
__device__ __forceinline__ void k1_work(
    const float* __restrict__ pred, const float* sbox, const int* slab,
    int b, int pix, float* slv, int* s_loc, float* f)
{
  constexpr int HW = H*W;
  const bool valid = (pix < HW);
  const int pp = valid ? pix : 0;
  const int h = pp / W, w = pp % W;
  const float cx = ((float)w + 0.5f)/(float)W;
  const float cy = ((float)h + 0.5f)/(float)H;
  const float THR = (SCALE==0) ? 1.0f : ((SCALE==1) ? 0.4f : 0.0f);

  const float* pb = pred + (size_t)b*CH*HW;
  float obj[3];
  #pragma unroll
  for (int a=0;a<3;a++) obj[a] = pb[(a*8+4)*HW + pp];   // coalesced

  float ax0[3],ay0[3],ax1[3],ay1[3],areaA[3];
  #pragma unroll
  for (int a=0;a<3;a++){
    const float sz=(a==0)?0.08f:((a==1)?0.16f:0.28f);
    const float hs=sz*0.5f;
    ax0[a]=cx-hs; ay0[a]=cy-hs; ax1[a]=cx+hs; ay1[a]=cy+hs;
    areaA[a]=(ax1[a]-ax0[a])*(ay1[a]-ay0[a]);
  }
  const float axr = cx + 0.14f, axl = cx - 0.14f;   // largest-anchor prune box
  const float ayr = cy + 0.14f, ayl = cy - 0.14f;

  float bi[3]={-1.f,-1.f,-1.f}, bu[3]={1.f,1.f,1.f};
  int bm[3]={0,0,0};
  #pragma unroll 4
  for (int m=0;m<MNUM;m++){
    const float bcx=sbox[4*m], bcy=sbox[4*m+1], bw=sbox[4*m+2], bh=sbox[4*m+3];
    const float bx0=bcx-bw*0.5f, by0=bcy-bh*0.5f, bx1=bcx+bw*0.5f, by1=bcy+bh*0.5f;
    const float iwb = fminf(axr,bx1) - fmaxf(axl,bx0);
    const float ihb = fminf(ayr,by1) - fmaxf(ayl,by0);
    if (iwb <= 0.f || ihb <= 0.f) continue;   // exact skip (monotone in hs)
    const float areaB=(bx1-bx0)*(by1-by0);
    #pragma unroll
    for (int a=0;a<3;a++){
      float iw=fminf(ax1[a],bx1)-fmaxf(ax0[a],bx0);
      float ih=fminf(ay1[a],by1)-fmaxf(ay0[a],by0);
      iw=fmaxf(iw,0.f); ih=fmaxf(ih,0.f);
      const float inter=iw*ih;
      const float uni=areaA[a]+areaB-inter+1e-9f;
      if (inter*bu[a] > bi[a]*uni){ bi[a]=inter; bu[a]=uni; bm[a]=m; }
    }
  }

  const int lane = threadIdx.x & 63;
  #pragma unroll
  for (int a=0;a<3;a++){
    const float best = bi[a]/bu[a];       // same operands as reference iou
    const bool pos = best >= 0.5f;
    const bool neg = best < 0.4f;
    const float o = obj[a];
    const float sp = log1pf(expf(-fabsf(o)));
    const float obj_all = fmaxf(o,0.f) - (pos? o:0.f) + sp;

    // wave-aggregated candidate push (<=768 per block; BCAP never overflows)
    const bool push = valid && neg && (obj_all >= THR);
    unsigned long long pm = __ballot(push ? 1 : 0);
    if (push){
      const int leader = (int)__ffsll((unsigned long long)pm) - 1;
      int wb2 = 0;
      if (lane == leader) wb2 = atomicAdd(s_loc, (int)__popcll(pm));
      wb2 = __shfl(wb2, leader, 64);
      slv[wb2 + (int)__popcll(pm & ((1ull<<lane)-1ull))] = obj_all;
    }

    if (valid){
      if (neg) f[1] += 1.f;
      if (pos){
        f[0]+=1.f; f[2]+=obj_all;
        const int midx=bm[a];
        int ct = slab[midx]-1; ct = ct<0?0:(ct>CNUM-1?CNUM-1:ct);
        const int cb=a*8;
        float c0=pb[(cb+5)*HW+pp], c1=pb[(cb+6)*HW+pp], c2=pb[(cb+7)*HW+pp];
        float mx=fmaxf(c0,fmaxf(c1,c2));
        float lse=mx+logf(expf(c0-mx)+expf(c1-mx)+expf(c2-mx));
        float csel=(ct==0)?c0:((ct==1)?c1:c2);
        f[3]+=lse-csel;
        const float sz=(a==0)?0.08f:((a==1)?0.16f:0.28f);
        float mcx=sbox[4*midx],mcy=sbox[4*midx+1],mw=sbox[4*midx+2],mh=sbox[4*midx+3];
        float t0=(mcx-cx)/sz,t1=(mcy-cy)/sz,t2=logf(mw/sz),t3=logf(mh/sz);
        float l0=pb[(cb+0)*HW+pp],l1=pb[(cb+1)*HW+pp],l2=pb[(cb+2)*HW+pp],l3=pb[(cb+3)*HW+pp];
        float ssum=0.f,d;
        d=fabsf(l0-t0); ssum+=(d<1.f)?(0.5f*d*d):(d-0.5f);
        d=fabsf(l1-t1); ssum+=(d<1.f)?(0.5f*d*d):(d-0.5f);
        d=fabsf(l2-t2); ssum+=(d<1.f)?(0.5f*d*d):(d-0.5f);
        d=fabsf(l3-t3); ssum+=(d<1.f)?(0.5f*d*d):(d-0.5f);
        f[4]+=ssum;
      }
    }
  }
}

// Full per-segment pipeline: anchor work -> flush -> arrival -> (last block)
// exact top-k over candidates -> loss -> (very last) output. Self-cleans.
template<int H, int W, int SCALE>
__device__ __forceinline__ void seg_run(
    const float* __restrict__ pred, const float* sbox, const int* slab,
    float* slv, int* p_sloc, float (*red)[4], int* hist, int* misc,
    float* fnp, int b, int cix, int nblk, float* scratch, float* out)
{
  constexpr int HW = H*W;
  constexpr int N = HW*ANUM;
  const int g = SCALE*BNUM + b;

  float f[5] = {0.f,0.f,0.f,0.f,0.f};
  k1_work<H,W,SCALE>(pred, sbox, slab, b, cix*256 + (int)threadIdx.x, slv, p_sloc, f);

  const int lane = threadIdx.x & 63, wv = threadIdx.x >> 6;
  __syncthreads();                      // all pushes done; s_loc final
  #pragma unroll
  for (int q=0;q<5;q++){
    float r = wred(f[q]);
    if (lane==0) red[q][wv] = r;
  }
  __syncthreads();
  if (threadIdx.x < 5){
    const int q = threadIdx.x;
    float t = red[q][0]+red[q][1]+red[q][2]+red[q][3];
    if (t != 0.f) atomicAdd(&g_acc[g*5+q], t);
  }
  const int n = *p_sloc;
  if (threadIdx.x == 0) misc[3] = (n > 0) ? atomicAdd(&g_ccnt[g], n) : 0;
  __syncthreads();
  const int gbase = misc[3];
  for (int i=threadIdx.x; i<n; i+=256){
    const int idx = gbase + i;
    if (idx < CAP) astore_f(&g_cand[(size_t)g*CAP + idx], slv[i]);
  }
  __syncthreads();                      // compiler drains vmcnt at barrier

  if (threadIdx.x==0) misc[2] = (arrive(&g_arr[g]) == nblk-1) ? 1 : 0;
  __syncthreads();
  if (!misc[2]) return;

  // ---------- fin (last block of this segment) ----------
  const int C_total = aload_i(&g_ccnt[g]);
  if (threadIdx.x==0){
    fnp[0] = aload_f(&g_acc[g*5+0]);
    fnp[1] = aload_f(&g_acc[g*5+1]);
  }
  __syncthreads();
  const float npos_f = fnp[0];
  const int npos = (int)(npos_f + 0.5f);
  const int avail = (int)(fnp[1] + 0.5f);
  const int k = (npos==0) ? (avail < 100 ? avail : 100)
                          : (3*npos < avail ? 3*npos : avail);

  float ss = 0.f, ns = 0.f;
  if (k > 0){
    const bool cpath = (C_total <= CAP) && (k <= C_total);
    const float* src; int M;
    if (cpath){
      src = g_cand + (size_t)g*CAP; M = C_total;
    } else {
      // fallback (provably dead on benign data): exact recompute
      for (int i=threadIdx.x; i<N; i+=256)
        scratch[i] = recompute_negval<H,W>(pred, sbox, b, i);
      __syncthreads();
      src = scratch; M = N;
    }
    // exact k-th largest via 4x8-bit MSB-first radix (values > 0: uint order)
    unsigned prefix = 0, pmask = 0; int rem = k;
    #pragma unroll
    for (int p=0;p<4;p++){
      const int shift = 24 - 8*p;
      hist[threadIdx.x] = 0;
      __syncthreads();
      for (int i=threadIdx.x; i<M; i+=256){
        float v = aload_f(src + i);
        unsigned u = __float_as_uint(v);
        const bool valid2 = (v >= 0.f) && ((u & pmask) == prefix);
        agg_hist_add(hist, (u>>shift)&255u, valid2);
      }
      __syncthreads();
      if (threadIdx.x==0){
        int cum=0;
        for (int j=255;j>=0;j--){
          cum += hist[j];
          if (cum >= rem){ misc[0]=j; misc[1] = rem-(cum-hist[j]); break; }
        }
      }
      __syncthreads();
      prefix |= ((unsigned)misc[0]) << shift;
      pmask  |= (255u << shift);
      rem = misc[1];
      __syncthreads();
    }
    const float thr = __uint_as_float(prefix);
    for (int i=threadIdx.x; i<M; i+=256){
      float v = aload_f(src + i);
      if (v >= thr){ ss += v; ns += 1.f; }   // thr > 0 excludes -1 sentinels
    }
  }

  float r0 = wred(ss), r1 = wred(ns);
  if (lane==0){ red[0][wv]=r0; red[1][wv]=r1; }
  __syncthreads();
  if (threadIdx.x==0){
    float sstot = red[0][0]+red[0][1]+red[0][2]+red[0][3];
    float nstot = red[1][0]+red[1][1]+red[1][2]+red[1][3];
    float cnt2 = npos_f + nstot;
    float ag2 = aload_f(&g_acc[g*5+2]);
    float ag3 = aload_f(&g_acc[g*5+3]);
    float ag4 = aload_f(&g_acc[g*5+4]);
    float lo = (cnt2 > 0.f) ? (ag2 + sstot)/cnt2 : 0.f;
    float lc = (npos > 0) ? ag3/npos_f : 0.f;
    float ll = (npos > 0) ? ag4/(npos_f*4.f) : 0.f;
    atomicAdd(&g_lsum[0], lo);
    atomicAdd(&g_lsum[1], lc);
    atomicAdd(&g_lsum[2], ll);
    if (arrive(&g_done) == NSEG-1){
      float L0 = aload_f(&g_lsum[0]);
      float L1 = aload_f(&g_lsum[1]);
      float L2 = aload_f(&g_lsum[2]);
      float lo2 = L0*(1.f/32.f), lc2 = L1*(1.f/32.f), ll2 = L2*(1.f/32.f);
      out[0]=lo2; out[1]=lc2; out[2]=ll2; out[3]=lo2+lc2+ll2;
      g_lsum[0]=0.f; g_lsum[1]=0.f; g_lsum[2]=0.f; g_done=0;
    }
  }

  // self-clean this segment's state for the next iteration
  __syncthreads();
  if (threadIdx.x < 5) g_acc[g*5 + threadIdx.x] = 0.f;
  if (threadIdx.x == 5) g_ccnt[g] = 0;
  if (threadIdx.x == 6) g_arr[g] = 0;
}

__global__ __launch_bounds__(256) void k_all(
    const float* __restrict__ pred0, const float* __restrict__ pred1,
    const float* __restrict__ pred2, const float* __restrict__ boxes,
    const int* __restrict__ labels, float* __restrict__ ws,
    float* __restrict__ out)
{
  __shared__ float sbox[MNUM*4];
  __shared__ int   slab[MNUM];
  __shared__ float slv[BCAP];          // 3 KB candidate buffer
  __shared__ int   s_loc;
  __shared__ float red[5][4];
  __shared__ int   hist[256];          // fin radix
  __shared__ int   misc[4];            // s_bin, s_rem, s_lastb, s_gbase
  __shared__ float fnp[2];

  const int b = blockIdx.y;
  if (threadIdx.x < MNUM*4) sbox[threadIdx.x] = boxes[b*MNUM*4 + threadIdx.x];
  else if (threadIdx.x < MNUM*5) slab[threadIdx.x - MNUM*4] = labels[b*MNUM + (threadIdx.x - MNUM*4)];
  if (threadIdx.x == 0) s_loc = 0;
  __syncthreads();

  const int c = blockIdx.x;   // 0..131 : 100 s0 + 25 s1 + 7 s2
  if (c < 100)
    seg_run<160,160,0>(pred0, sbox, slab, slv, &s_loc, red, hist, misc, fnp,
                       b, c, 100, ws + (size_t)b*76800, out);
  else if (c < 125)
    seg_run<80,80,1>(pred1, sbox, slab, slv, &s_loc, red, hist, misc, fnp,
                     b, c-100, 25, ws + (size_t)BNUM*76800 + (size_t)b*19200, out);
  else
    seg_run<40,40,2>(pred2, sbox, slab, slv, &s_loc, red, hist, misc, fnp,
                     b, c-125, 7, ws + (size_t)BNUM*(76800+19200) + (size_t)b*4800, out);
}

extern "C" void kernel_launch(void* const* d_in, const int* in_sizes, int n_in,
                              void* d_out, int out_size, void* d_ws, size_t ws_size,
                              hipStream_t stream)
{
  const float* pred0 = (const float*)d_in[0];
  const float* pred1 = (const float*)d_in[1];
  const float* pred2 = (const float*)d_in[2];
  const float* boxes = (const float*)d_in[6];
  const int*   labels = (const int*)d_in[7];
  float* out = (float*)d_out;
  float* ws  = (float*)d_ws;    // scratch used ONLY by the exact fallback

  k_all<<<dim3(132,32), 256, 0, stream>>>(pred0, pred1, pred2, boxes, labels, ws, out);
}

// Round 12
// 387.820 us; speedup vs baseline: 2.9253x; 1.0177x over previous
//
#include <hip/hip_runtime.h>
#include <math.h>

#define ANUM 3
#define CNUM 3
#define BNUM 32
#define MNUM 16
#define CH 24      // ANUM*(5+CNUM)
#define NSEG 96
#define CAP 32768  // per-segment candidate capacity (12.6 MB static)
#define BCAP 768   // per-block max pushes = 256 threads * 3 anchors (no overflow)

// All cross-block state in static device memory (zero-initialized at load).
// Each iteration self-cleans -> no init kernel needed.
__device__ __align__(16) float g_cand[(size_t)NSEG*CAP];
__device__ int   g_ccnt[NSEG];
__device__ float g_acc[NSEG*5];
__device__ float g_lsum[3];
__device__ int   g_arr[NSEG];
__device__ int   g_done;

__device__ __forceinline__ float wred(float v){
  #pragma unroll
  for (int off=32; off; off>>=1) v += __shfl_down(v, off, 64);
  return v;
}

// Relaxed agent-scope arrival (r8/r9: acq_rel causes L2 wb/inv storms;
// relaxed + vmcnt(0) suffices: all cross-block data moves through
// coherence-point atomics).
__device__ __forceinline__ int arrive(int* ctr){
  asm volatile("s_waitcnt vmcnt(0)" ::: "memory");
  return __hip_atomic_fetch_add(ctr, 1, __ATOMIC_RELAXED, __HIP_MEMORY_SCOPE_AGENT);
}
__device__ __forceinline__ int aload_i(const int* p){
  return __hip_atomic_load(p, __ATOMIC_RELAXED, __HIP_MEMORY_SCOPE_AGENT);
}
__device__ __forceinline__ float aload_f(const float* p){
  return __hip_atomic_load(p, __ATOMIC_RELAXED, __HIP_MEMORY_SCOPE_AGENT);
}
__device__ __forceinline__ void astore_f(float* p, float v){
  __hip_atomic_store(p, v, __ATOMIC_RELAXED, __HIP_MEMORY_SCOPE_AGENT);
}

// Wave-aggregated histogram add (proven r1/r2/r11): lanes with equal bin
// elect a leader doing ONE atomicAdd of popcount(peers). Essential for
// tail-concentrated values (r10's 64-way serialization pathology).
__device__ __forceinline__ void agg_hist_add(int* hist, unsigned bin, bool valid){
  unsigned long long peers = __ballot(valid ? 1 : 0);
  #pragma unroll
  for (int i = 0; i < 8; i++){
    unsigned long long bb = __ballot((valid && (bin & (1u<<i))) ? 1 : 0);
    peers &= ((bin >> i) & 1u) ? bb : ~bb;
  }
  if (valid){
    const int lane = threadIdx.x & 63;
    if ((peers & ((1ull << lane) - 1ull)) == 0ull)
      atomicAdd(&hist[bin], (int)__popcll(peers));
  }
}

// Exact per-anchor recompute for the (provably-dead on benign data)
// fallback path.
template<int H, int W>
__device__ float recompute_negval(const float* __restrict__ pred,
    const float* sbox, int b, int n)
{
  constexpr int HW = H*W;
  const int a = n % 3;
  const int pixn = n / 3;
  const int h = pixn / W, w = pixn % W;
  const float cx = ((float)w+0.5f)/(float)W;
  const float cy = ((float)h+0.5f)/(float)H;
  const float sz = (a==0)?0.08f:((a==1)?0.16f:0.28f);
  const float hs = sz*0.5f;
  const float ax0=cx-hs, ay0=cy-hs, ax1=cx+hs, ay1=cy+hs;
  const float areaA=(ax1-ax0)*(ay1-ay0);
  float bi=-1.f, bu=1.f;
  for (int m=0;m<MNUM;m++){
    const float bcx=sbox[4*m], bcy=sbox[4*m+1], bw=sbox[4*m+2], bh=sbox[4*m+3];
    const float bx0=bcx-bw*0.5f, by0=bcy-bh*0.5f, bx1=bcx+bw*0.5f, by1=bcy+bh*0.5f;
    float iw=fminf(ax1,bx1)-fmaxf(ax0,bx0);
    float ih=fminf(ay1,by1)-fmaxf(ay0,by0);
    iw=fmaxf(iw,0.f); ih=fmaxf(ih,0.f);
    const float inter=iw*ih;
    const float areaB=(bx1-bx0)*(by1-by0);
    const float uni=areaA+areaB-inter+1e-9f;
    if (inter*bu > bi*uni){ bi=inter; bu=uni; }
  }
  const float best=bi/bu;
  const bool pos = best>=0.5f;
  const bool neg = best<0.4f;
  const float o = pred[(size_t)b*CH*HW + (a*8+4)*HW + pixn];
  const float sp = log1pf(expf(-fabsf(o)));
  const float obj_all = fmaxf(o,0.f) - (pos?o:0.f) + sp;
  return neg ? obj_all : -1.f;
}

// Per-pixel anchor work: prune, classify, losses, candidate push.
// THR per scale: candidates provably cover top-k (r11-verified: cpath held).
template<int H, int W, int SCALE>
__device__ __forceinline__ void k1_work(
    const float* __restrict__ pred, const float* sbox, const int* slab,
    int b, int pix, float* slv, int* s_loc, float* f)
{
  constexpr int HW = H*W;
  const bool valid = (pix < HW);
  const int pp = valid ? pix : 0;
  const int h = pp / W, w = pp % W;
  const float cx = ((float)w + 0.5f)/(float)W;
  const float cy = ((float)h + 0.5f)/(float)H;
  const float THR = (SCALE==0) ? 1.0f : ((SCALE==1) ? 0.4f : 0.0f);

  const float* pb = pred + (size_t)b*CH*HW;
  float obj[3];
  #pragma unroll
  for (int a=0;a<3;a++) obj[a] = pb[(a*8+4)*HW + pp];   // coalesced

  float ax0[3],ay0[3],ax1[3],ay1[3],areaA[3];
  #pragma unroll
  for (int a=0;a<3;a++){
    const float sz=(a==0)?0.08f:((a==1)?0.16f:0.28f);
    const float hs=sz*0.5f;
    ax0[a]=cx-hs; ay0[a]=cy-hs; ax1[a]=cx+hs; ay1[a]=cy+hs;
    areaA[a]=(ax1[a]-ax0[a])*(ay1[a]-ay0[a]);
  }
  const float axr = cx + 0.14f, axl = cx - 0.14f;   // largest-anchor prune box
  const float ayr = cy + 0.14f, ayl = cy - 0.14f;

  float bi[3]={-1.f,-1.f,-1.f}, bu[3]={1.f,1.f,1.f};
  int bm[3]={0,0,0};
  #pragma unroll 4
  for (int m=0;m<MNUM;m++){
    const float bcx=sbox[4*m], bcy=sbox[4*m+1], bw=sbox[4*m+2], bh=sbox[4*m+3];
    const float bx0=bcx-bw*0.5f, by0=bcy-bh*0.5f, bx1=bcx+bw*0.5f, by1=bcy+bh*0.5f;
    const float iwb = fminf(axr,bx1) - fmaxf(axl,bx0);
    const float ihb = fminf(ayr,by1) - fmaxf(ayl,by0);
    if (iwb <= 0.f || ihb <= 0.f) continue;   // exact skip (monotone in hs)
    const float areaB=(bx1-bx0)*(by1-by0);
    #pragma unroll
    for (int a=0;a<3;a++){
      float iw=fminf(ax1[a],bx1)-fmaxf(ax0[a],bx0);
      float ih=fminf(ay1[a],by1)-fmaxf(ay0[a],by0);
      iw=fmaxf(iw,0.f); ih=fmaxf(ih,0.f);
      const float inter=iw*ih;
      const float uni=areaA[a]+areaB-inter+1e-9f;
      if (inter*bu[a] > bi[a]*uni){ bi[a]=inter; bu[a]=uni; bm[a]=m; }
    }
  }

  const int lane = threadIdx.x & 63;
  #pragma unroll
  for (int a=0;a<3;a++){
    const float best = bi[a]/bu[a];       // same operands as reference iou
    const bool pos = best >= 0.5f;
    const bool neg = best < 0.4f;
    const float o = obj[a];
    const float sp = log1pf(expf(-fabsf(o)));
    const float obj_all = fmaxf(o,0.f) - (pos? o:0.f) + sp;

    // wave-aggregated candidate push (<=768 per block; BCAP never overflows)
    const bool push = valid && neg && (obj_all >= THR);
    unsigned long long pm = __ballot(push ? 1 : 0);
    if (push){
      const int leader = (int)__ffsll((unsigned long long)pm) - 1;
      int wb2 = 0;
      if (lane == leader) wb2 = atomicAdd(s_loc, (int)__popcll(pm));
      wb2 = __shfl(wb2, leader, 64);
      slv[wb2 + (int)__popcll(pm & ((1ull<<lane)-1ull))] = obj_all;
    }

    if (valid){
      if (neg) f[1] += 1.f;
      if (pos){
        f[0]+=1.f; f[2]+=obj_all;
        const int midx=bm[a];
        int ct = slab[midx]-1; ct = ct<0?0:(ct>CNUM-1?CNUM-1:ct);
        const int cb=a*8;
        float c0=pb[(cb+5)*HW+pp], c1=pb[(cb+6)*HW+pp], c2=pb[(cb+7)*HW+pp];
        float mx=fmaxf(c0,fmaxf(c1,c2));
        float lse=mx+logf(expf(c0-mx)+expf(c1-mx)+expf(c2-mx));
        float csel=(ct==0)?c0:((ct==1)?c1:c2);
        f[3]+=lse-csel;
        const float sz=(a==0)?0.08f:((a==1)?0.16f:0.28f);
        float mcx=sbox[4*midx],mcy=sbox[4*midx+1],mw=sbox[4*midx+2],mh=sbox[4*midx+3];
        float t0=(mcx-cx)/sz,t1=(mcy-cy)/sz,t2=logf(mw/sz),t3=logf(mh/sz);
        float l0=pb[(cb+0)*HW+pp],l1=pb[(cb+1)*HW+pp],l2=pb[(cb+2)*HW+pp],l3=pb[(cb+3)*HW+pp];
        float ssum=0.f,d;
        d=fabsf(l0-t0); ssum+=(d<1.f)?(0.5f*d*d):(d-0.5f);
        d=fabsf(l1-t1); ssum+=(d<1.f)?(0.5f*d*d):(d-0.5f);
        d=fabsf(l2-t2); ssum+=(d<1.f)?(0.5f*d*d):(d-0.5f);
        d=fabsf(l3-t3); ssum+=(d<1.f)?(0.5f*d*d):(d-0.5f);
        f[4]+=ssum;
      }
    }
  }
}

// Full per-segment pipeline: anchor work -> flush -> arrival -> (last block)
// exact top-k over candidates -> loss -> (very last) output. Self-cleans.
template<int H, int W, int SCALE>
__device__ __forceinline__ void seg_run(
    const float* __restrict__ pred, const float* sbox, const int* slab,
    float* slv, int* p_sloc, float (*red)[4], int* hist, int* misc,
    float* fnp, int b, int cix, int nblk, float* scratch, float* out)
{
  constexpr int HW = H*W;
  constexpr int N = HW*ANUM;
  const int g = SCALE*BNUM + b;

  float f[5] = {0.f,0.f,0.f,0.f,0.f};
  k1_work<H,W,SCALE>(pred, sbox, slab, b, cix*256 + (int)threadIdx.x, slv, p_sloc, f);

  const int lane = threadIdx.x & 63, wv = threadIdx.x >> 6;
  __syncthreads();                      // all pushes done; s_loc final
  #pragma unroll
  for (int q=0;q<5;q++){
    float r = wred(f[q]);
    if (lane==0) red[q][wv] = r;
  }
  __syncthreads();
  if (threadIdx.x < 5){
    const int q = threadIdx.x;
    float t = red[q][0]+red[q][1]+red[q][2]+red[q][3];
    if (t != 0.f) atomicAdd(&g_acc[g*5+q], t);
  }
  const int n = *p_sloc;
  if (threadIdx.x == 0) misc[3] = (n > 0) ? atomicAdd(&g_ccnt[g], n) : 0;
  __syncthreads();
  const int gbase = misc[3];
  for (int i=threadIdx.x; i<n; i+=256){
    const int idx = gbase + i;
    if (idx < CAP) astore_f(&g_cand[(size_t)g*CAP + idx], slv[i]);
  }
  __syncthreads();                      // compiler drains vmcnt at barrier

  if (threadIdx.x==0) misc[2] = (arrive(&g_arr[g]) == nblk-1) ? 1 : 0;
  __syncthreads();
  if (!misc[2]) return;

  // ---------- fin (last block of this segment) ----------
  const int C_total = aload_i(&g_ccnt[g]);
  if (threadIdx.x==0){
    fnp[0] = aload_f(&g_acc[g*5+0]);
    fnp[1] = aload_f(&g_acc[g*5+1]);
  }
  __syncthreads();
  const float npos_f = fnp[0];
  const int npos = (int)(npos_f + 0.5f);
  const int avail = (int)(fnp[1] + 0.5f);
  const int k = (npos==0) ? (avail < 100 ? avail : 100)
                          : (3*npos < avail ? 3*npos : avail);

  float ss = 0.f, ns = 0.f;
  if (k > 0){
    const bool cpath = (C_total <= CAP) && (k <= C_total);
    int M;
    if (cpath){
      // Stage candidates -> own scratch. Batched aloads (8 in flight ->
      // latency hidden; r11's pathology was 1-at-a-time aloads under
      // ballot reconvergence). Same-block plain store->load is coherent.
      M = C_total;
      const float* gc = g_cand + (size_t)g*CAP;
      for (int base = 0; base < M; base += 2048){
        float v[8];
        #pragma unroll
        for (int j=0;j<8;j++){
          const int idx = base + j*256 + (int)threadIdx.x;
          v[j] = (idx < M) ? aload_f(gc + idx) : -1.f;
        }
        #pragma unroll
        for (int j=0;j<8;j++){
          const int idx = base + j*256 + (int)threadIdx.x;
          if (idx < M) scratch[idx] = v[j];
        }
      }
    } else {
      // fallback (provably dead on benign data): exact recompute
      for (int i=threadIdx.x; i<N; i+=256)
        scratch[i] = recompute_negval<H,W>(pred, sbox, b, i);
      M = N;
    }
    __syncthreads();

    // exact k-th largest via 4x8-bit MSB-first radix over L2-hot scratch
    // (batched plain loads + wave-aggregated hist adds)
    unsigned prefix = 0, pmask = 0; int rem = k;
    #pragma unroll
    for (int p=0;p<4;p++){
      const int shift = 24 - 8*p;
      hist[threadIdx.x] = 0;
      __syncthreads();
      for (int base = 0; base < M; base += 2048){
        float v[8];
        #pragma unroll
        for (int j=0;j<8;j++){
          const int idx = base + j*256 + (int)threadIdx.x;
          v[j] = (idx < M) ? scratch[idx] : -1.f;
        }
        #pragma unroll
        for (int j=0;j<8;j++){
          const unsigned u = __float_as_uint(v[j]);
          const bool valid2 = (v[j] >= 0.f) && ((u & pmask) == prefix);
          agg_hist_add(hist, (u>>shift)&255u, valid2);
        }
      }
      __syncthreads();
      if (threadIdx.x==0){
        int cum=0;
        for (int j=255;j>=0;j--){
          cum += hist[j];
          if (cum >= rem){ misc[0]=j; misc[1] = rem-(cum-hist[j]); break; }
        }
      }
      __syncthreads();
      prefix |= ((unsigned)misc[0]) << shift;
      pmask  |= (255u << shift);
      rem = misc[1];
      __syncthreads();
    }
    const float thr = __uint_as_float(prefix);
    for (int i=threadIdx.x; i<M; i+=256){
      float v = scratch[i];
      if (v >= thr){ ss += v; ns += 1.f; }   // thr > 0 excludes -1 sentinels
    }
  }

  float r0 = wred(ss), r1 = wred(ns);
  if (lane==0){ red[0][wv]=r0; red[1][wv]=r1; }
  __syncthreads();
  if (threadIdx.x==0){
    float sstot = red[0][0]+red[0][1]+red[0][2]+red[0][3];
    float nstot = red[1][0]+red[1][1]+red[1][2]+red[1][3];
    float cnt2 = npos_f + nstot;
    float ag2 = aload_f(&g_acc[g*5+2]);
    float ag3 = aload_f(&g_acc[g*5+3]);
    float ag4 = aload_f(&g_acc[g*5+4]);
    float lo = (cnt2 > 0.f) ? (ag2 + sstot)/cnt2 : 0.f;
    float lc = (npos > 0) ? ag3/npos_f : 0.f;
    float ll = (npos > 0) ? ag4/(npos_f*4.f) : 0.f;
    atomicAdd(&g_lsum[0], lo);
    atomicAdd(&g_lsum[1], lc);
    atomicAdd(&g_lsum[2], ll);
    if (arrive(&g_done) == NSEG-1){
      float L0 = aload_f(&g_lsum[0]);
      float L1 = aload_f(&g_lsum[1]);
      float L2 = aload_f(&g_lsum[2]);
      float lo2 = L0*(1.f/32.f), lc2 = L1*(1.f/32.f), ll2 = L2*(1.f/32.f);
      out[0]=lo2; out[1]=lc2; out[2]=ll2; out[3]=lo2+lc2+ll2;
      g_lsum[0]=0.f; g_lsum[1]=0.f; g_lsum[2]=0.f; g_done=0;
    }
  }

  // self-clean this segment's state for the next iteration
  __syncthreads();
  if (threadIdx.x < 5) g_acc[g*5 + threadIdx.x] = 0.f;
  if (threadIdx.x == 5) g_ccnt[g] = 0;
  if (threadIdx.x == 6) g_arr[g] = 0;
}

__global__ __launch_bounds__(256) void k_all(
    const float* __restrict__ pred0, const float* __restrict__ pred1,
    const float* __restrict__ pred2, const float* __restrict__ boxes,
    const int* __restrict__ labels, float* __restrict__ ws,
    float* __restrict__ out)
{
  __shared__ float sbox[MNUM*4];
  __shared__ int   slab[MNUM];
  __shared__ float slv[BCAP];          // 3 KB candidate buffer
  __shared__ int   s_loc;
  __shared__ float red[5][4];
  __shared__ int   hist[256];          // fin radix
  __shared__ int   misc[4];            // s_bin, s_rem, s_lastb, s_gbase
  __shared__ float fnp[2];

  const int b = blockIdx.y;
  if (threadIdx.x < MNUM*4) sbox[threadIdx.x] = boxes[b*MNUM*4 + threadIdx.x];
  else if (threadIdx.x < MNUM*5) slab[threadIdx.x - MNUM*4] = labels[b*MNUM + (threadIdx.x - MNUM*4)];
  if (threadIdx.x == 0) s_loc = 0;
  __syncthreads();

  const int c = blockIdx.x;   // 0..131 : 100 s0 + 25 s1 + 7 s2
  if (c < 100)
    seg_run<160,160,0>(pred0, sbox, slab, slv, &s_loc, red, hist, misc, fnp,
                       b, c, 100, ws + (size_t)b*76800, out);
  else if (c < 125)
    seg_run<80,80,1>(pred1, sbox, slab, slv, &s_loc, red, hist, misc, fnp,
                     b, c-100, 25, ws + (size_t)BNUM*76800 + (size_t)b*19200, out);
  else
    seg_run<40,40,2>(pred2, sbox, slab, slv, &s_loc, red, hist, misc, fnp,
                     b, c-125, 7, ws + (size_t)BNUM*(76800+19200) + (size_t)b*4800, out);
}

extern "C" void kernel_launch(void* const* d_in, const int* in_sizes, int n_in,
                              void* d_out, int out_size, void* d_ws, size_t ws_size,
                              hipStream_t stream)
{
  const float* pred0 = (const float*)d_in[0];
  const float* pred1 = (const float*)d_in[1];
  const float* pred2 = (const float*)d_in[2];
  const float* boxes = (const float*)d_in[6];
  const int*   labels = (const int*)d_in[7];
  float* out = (float*)d_out;
  float* ws  = (float*)d_ws;    // per-segment fin scratch

  k_all<<<dim3(132,32), 256, 0, stream>>>(pred0, pred1, pred2, boxes, labels, ws, out);
}